// Round 6
// baseline (269.541 us; speedup 1.0000x reference)
//
#include <hip/hip_runtime.h>
#include <cmath>

// Outputs concatenated flat (all float32):
//   [0)      N*N*3 : dxyz_m
//   [N*N*3)  N*N   : buckets
//   [N*N*4)  N*N   : dscanid
//   [N*N*5)  N*N   : mask
//
// Linear-sweep design: thread t owns out[4t..4t+3] (one 16B chunk). Blocks in
// ascending blockIdx sweep `out` linearly (like the harness's fillBuffer), so
// the device-wide write front is a narrow moving window -> HBM page locality.
// Each thread recomputes the pair math for the elements it writes.

__device__ __forceinline__ float bucket_base(float v) {
    // x = v / RES (RES=0.5 -> exact *2)
    const float x  = v * 2.0f;
    const float xa = fabsf(x);
    if (xa <= 2.0f) {
        return 8.0f + rintf(x); // round-half-to-even like jnp.round
    }
    const float lr = logf(fmaxf(xa, 1e-6f) * 0.5f) / 2.0794415416798357f; // /log(8)
    const float sup = fminf(rintf(2.0f - 6.0f * lr), 8.0f);
    return 8.0f + ((x > 0.0f) ? sup : -sup);
}

// Full mask + masked deltas for a single pair p = i*N + j.
template<int CN>
__device__ __forceinline__ void one_pair(
    const float* __restrict__ xyz, const int* __restrict__ grid,
    int Nrt, int p, float& dxm, float& dym, float& dzm)
{
#pragma clang fp contract(off)
    const int N = CN ? CN : Nrt;
    const int i = (int)((unsigned)p / (unsigned)N);
    const int j = p - i * N;
    const float xi = xyz[3*i+0], yi = xyz[3*i+1], zi = xyz[3*i+2];
    const float xj = xyz[3*j+0], yj = xyz[3*j+1], zj = xyz[3*j+2];
    const int bat_i = grid[5*i+0], blk_i = grid[5*i+1];
    const int c0i = grid[5*i+2], c1i = grid[5*i+3], c2i = grid[5*i+4];
    const int bat_j = grid[5*j+0], blk_j = grid[5*j+1];
    const int c0j = grid[5*j+2], c1j = grid[5*j+3], c2j = grid[5*j+4];
    const float dx = xi - xj, dy = yi - yj, dz = zi - zj;
    const bool batch_eq = (bat_i == bat_j);
    const bool block_le = (blk_i <= blk_j);
    const int  cadj = max(max(abs(c0i-c0j), abs(c1i-c1j)), abs(c2i-c2j));
    const bool forcekeep = (cadj <= 1) && (blk_i == blk_j);
    const int xci = (int)ceilf(xi/3.0f), yci = (int)ceilf(yi/3.0f);
    const int xcj = (int)ceilf(xj/3.0f), ycj = (int)ceilf(yj/3.0f);
    const bool keep_coarse = max(abs(xci-xcj), abs(yci-ycj)) <= 1;
    const float d2 = dx*dx + dy*dy + dz*dz; // contract(off): matches ref
    const bool keepr = (d2 <= 9.0f);
    const bool m = batch_eq && block_le &&
                   (forcekeep || keep_coarse) && (forcekeep || keepr);
    dxm = m ? dx : 0.0f; dym = m ? dy : 0.0f; dzm = m ? dz : 0.0f;
}

// Mask + masked deltas for 4 consecutive pairs (i, j0..j0+3), j0 % 4 == 0.
__device__ __forceinline__ void quad_mask(
    const float* __restrict__ xyz, const int* __restrict__ grid,
    int i, int j0,
    float dxm[4], float dym[4], float dzm[4], bool mk[4],
    int jblk[4], int& blk_i, bool& any)
{
#pragma clang fp contract(off)
    const float xi = xyz[3*i+0], yi = xyz[3*i+1], zi = xyz[3*i+2];
    const int bat_i = grid[5*i+0]; blk_i = grid[5*i+1];
    const int c0i = grid[5*i+2], c1i = grid[5*i+3], c2i = grid[5*i+4];
    const int xci = (int)ceilf(xi/3.0f), yci = (int)ceilf(yi/3.0f);

    const float4* pv = reinterpret_cast<const float4*>(xyz + (size_t)3 * j0);
    const float4 p0 = pv[0], p1 = pv[1], p2 = pv[2];
    const int4* gv = reinterpret_cast<const int4*>(grid + (size_t)5 * j0);
    const int4 g0 = gv[0], g1 = gv[1], g2 = gv[2], g3 = gv[3], g4 = gv[4];

    const float jx[4]  = {p0.x, p0.w, p1.z, p2.y};
    const float jy[4]  = {p0.y, p1.x, p1.w, p2.z};
    const float jz[4]  = {p0.z, p1.y, p2.x, p2.w};
    const int   jbat[4] = {g0.x, g1.y, g2.z, g3.w};
    const int   jb[4]   = {g0.y, g1.z, g2.w, g4.x};
    const int   jc0[4]  = {g0.z, g1.w, g3.x, g4.y};
    const int   jc1[4]  = {g0.w, g2.x, g3.y, g4.z};
    const int   jc2[4]  = {g1.x, g2.y, g3.z, g4.w};

    any = false;
#pragma unroll
    for (int k = 0; k < 4; ++k) {
        const float dx = xi - jx[k];
        const float dy = yi - jy[k];
        const float dz = zi - jz[k];
        const bool batch_eq = (bat_i == jbat[k]);
        const bool block_le = (blk_i <= jb[k]);
        const int  cadj = max(max(abs(c0i - jc0[k]), abs(c1i - jc1[k])),
                              abs(c2i - jc2[k]));
        const bool forcekeep = (cadj <= 1) && (blk_i == jb[k]);
        const int xcj = (int)ceilf(jx[k] / 3.0f);
        const int ycj = (int)ceilf(jy[k] / 3.0f);
        const bool keep_coarse = max(abs(xci - xcj), abs(yci - ycj)) <= 1;
        const float d2 = dx * dx + dy * dy + dz * dz; // contract(off)
        const bool keepr = (d2 <= 9.0f);
        const bool m = batch_eq && block_le &&
                       (forcekeep || keep_coarse) && (forcekeep || keepr);
        mk[k] = m; any |= m;
        jblk[k] = jb[k];
        dxm[k] = m ? dx : 0.0f;
        dym[k] = m ? dy : 0.0f;
        dzm[k] = m ? dz : 0.0f;
    }
}

template<int CN>
__global__ __launch_bounds__(256) void linear_kernel(
    const float* __restrict__ xyz, const int* __restrict__ grid,
    float* __restrict__ out, int Nrt)
{
    const int N = CN ? CN : Nrt;
    const unsigned NN = (unsigned)N * (unsigned)N;
    const unsigned t = blockIdx.x * blockDim.x + threadIdx.x;
    const unsigned e = t * 4u;              // float offset into out
    if (e >= 6u * NN) return;
    float4* dst = reinterpret_cast<float4*>(out + (size_t)e);

    if (e < 3u * NN) {
        // ---- dxyz region: elements straddle at most 2 pairs ----
        const unsigned c0 = e % 3u;
        const int p0 = (int)(e / 3u);
        float a0, a1, a2, b0, b1, b2;
        one_pair<CN>(xyz, grid, N, p0,     a0, a1, a2);
        one_pair<CN>(xyz, grid, N, p0 + 1, b0, b1, b2);
        float4 v;
        if (c0 == 0u)      v = make_float4(a0, a1, a2, b0);
        else if (c0 == 1u) v = make_float4(a1, a2, b0, b1);
        else               v = make_float4(a2, b0, b1, b2);
        *dst = v;
        return;
    }

    // scalar regions: 4 consecutive pairs, same i (N % 4 == 0)
    float dx[4], dy[4], dz[4];
    bool  mk[4];
    int   jblk[4], blk_i;
    bool  any;

    if (e < 4u * NN) {
        // ---- buckets ----
        const int p = (int)(e - 3u * NN);
        const int i = (int)((unsigned)p / (unsigned)N);
        const int j0 = p - i * N;
        quad_mask(xyz, grid, i, j0, dx, dy, dz, mk, jblk, blk_i, any);
        if (__ballot(any ? 1 : 0) == 0ULL) {
            *dst = make_float4(0.0f, 0.0f, 0.0f, 0.0f);
            return;
        }
        float bf[4];
#pragma unroll
        for (int k = 0; k < 4; ++k) {
            if (mk[k]) {
                const float q0 = bucket_base(dx[k]);
                const float q1 = bucket_base(dy[k]);
                const float q2 = bucket_base(dz[k]);
                const float bsum = (289.0f * q0 + 17.0f * q1) + q2; // exact small ints
                bf[k] = (float)(int)bsum;
            } else {
                bf[k] = 0.0f;
            }
        }
        *dst = make_float4(bf[0], bf[1], bf[2], bf[3]);
    } else if (e < 5u * NN) {
        // ---- dscanid ----
        const int p = (int)(e - 4u * NN);
        const int i = (int)((unsigned)p / (unsigned)N);
        const int j0 = p - i * N;
        quad_mask(xyz, grid, i, j0, dx, dy, dz, mk, jblk, blk_i, any);
        const int scan_i = blk_i >> 1;
        float df[4];
#pragma unroll
        for (int k = 0; k < 4; ++k)
            df[k] = mk[k] ? (float)((jblk[k] >> 1) - scan_i) : 0.0f;
        *dst = make_float4(df[0], df[1], df[2], df[3]);
    } else {
        // ---- mask ----
        const int p = (int)(e - 5u * NN);
        const int i = (int)((unsigned)p / (unsigned)N);
        const int j0 = p - i * N;
        quad_mask(xyz, grid, i, j0, dx, dy, dz, mk, jblk, blk_i, any);
        float mf[4];
#pragma unroll
        for (int k = 0; k < 4; ++k)
            mf[k] = mk[k] ? 1.0f : 0.0f;
        *dst = make_float4(mf[0], mf[1], mf[2], mf[3]);
    }
}

extern "C" void kernel_launch(void* const* d_in, const int* in_sizes, int n_in,
                              void* d_out, int out_size, void* d_ws, size_t ws_size,
                              hipStream_t stream) {
    const float* xyz  = (const float*)d_in[0];
    const int*   grid = (const int*)d_in[1];
    float*       out  = (float*)d_out;
    const int N = in_sizes[0] / 3; // xyz is (N,3); N=3072 in the bench

    const unsigned total  = 6u * (unsigned)N * (unsigned)N; // floats in out
    const unsigned threads = (total + 3u) / 4u;
    const int BLOCK = 256;
    const unsigned blocks = (threads + BLOCK - 1) / BLOCK;
    if (N == 3072) {
        linear_kernel<3072><<<blocks, BLOCK, 0, stream>>>(xyz, grid, out, N);
    } else {
        linear_kernel<0><<<blocks, BLOCK, 0, stream>>>(xyz, grid, out, N);
    }
}